// Round 1
// baseline (402.692 us; speedup 1.0000x reference)
//
#include <hip/hip_runtime.h>
#include <math.h>

// Problem constants (fixed by the reference):
#define NEXP 4               // n
#define STREAM 4096          // N*C
#define NOUT 24              // n*n + 2n
#define NTOK 16384           // B*L
#define SK_ITERS 20

// Kernel B tiling:
#define T_PER_BLOCK 8        // tokens per block (phi reuse factor)
#define CHUNK 512            // k-values staged per chunk
#define NCHUNK (STREAM / CHUNK)   // 8

// ---------------------------------------------------------------------------
// Kernel A: phiT[j][k] = scale[k] * phi[k][j]   (24 x 4096, transposed+scaled)
// ---------------------------------------------------------------------------
__global__ __launch_bounds__(256) void k_transpose_scale(
    const float* __restrict__ phi, const float* __restrict__ scale,
    float* __restrict__ phiT) {
  int flat = blockIdx.x * 256 + threadIdx.x;   // 0..98303, flat = k*24 + j
  int k = flat / NOUT;
  int j = flat - k * NOUT;
  phiT[j * STREAM + k] = phi[flat] * scale[k];
}

// ---------------------------------------------------------------------------
// Kernel B: per token, sumsq + 24-way dot, m = dot/rms + bias -> m_buf
//   block = 256 threads (4 waves), 8 tokens per block.
//   wave w: stages tokens 2w,2w+1 into LDS + their sumsq; computes j-range
//   [6w, 6w+6) for ALL 8 tokens (phi read once per block).
// ---------------------------------------------------------------------------
__global__ __launch_bounds__(256) void k_matvec(
    const float* __restrict__ x, const float* __restrict__ phiT,
    const float* __restrict__ bias, float* __restrict__ m_buf) {
  __shared__ float lds_x[T_PER_BLOCK * CHUNK];   // 16 KB
  __shared__ float lds_inv[T_PER_BLOCK];         // 1/rms per token

  const int tid  = threadIdx.x;
  const int w    = tid >> 6;
  const int lane = tid & 63;
  const int tok0 = blockIdx.x * T_PER_BLOCK;

  const float4* x4    = (const float4*)x;
  const float4* phiT4 = (const float4*)phiT;
  float4*       lds4  = (float4*)lds_x;

  float acc[T_PER_BLOCK][6];
#pragma unroll
  for (int t = 0; t < T_PER_BLOCK; t++)
#pragma unroll
    for (int jj = 0; jj < 6; jj++) acc[t][jj] = 0.0f;
  float ssq0 = 0.0f, ssq1 = 0.0f;

  for (int ch = 0; ch < NCHUNK; ch++) {
    // ---- stage: wave w loads tokens 2w and 2w+1 (128 float4 each) ----
#pragma unroll
    for (int tl = 0; tl < 2; tl++) {
      int t = 2 * w + tl;
      int tok = tok0 + t;
#pragma unroll
      for (int i = 0; i < 2; i++) {
        int pos4 = i * 64 + lane;
        float4 v = x4[tok * (STREAM / 4) + ch * (CHUNK / 4) + pos4];
        lds4[t * (CHUNK / 4) + pos4] = v;
        float s = v.x * v.x + v.y * v.y + v.z * v.z + v.w * v.w;
        if (tl == 0) ssq0 += s; else ssq1 += s;
      }
    }
    __syncthreads();
    // ---- compute: 6 phi columns (j = 6w+jj) x 8 tokens ----
#pragma unroll
    for (int i = 0; i < 2; i++) {
      int k4 = i * 64 + lane;
      float4 p[6];
#pragma unroll
      for (int jj = 0; jj < 6; jj++)
        p[jj] = phiT4[(6 * w + jj) * (STREAM / 4) + ch * (CHUNK / 4) + k4];
#pragma unroll
      for (int t = 0; t < T_PER_BLOCK; t++) {
        float4 xv = lds4[t * (CHUNK / 4) + k4];
#pragma unroll
        for (int jj = 0; jj < 6; jj++) {
          float a = acc[t][jj];
          a = fmaf(xv.x, p[jj].x, a);
          a = fmaf(xv.y, p[jj].y, a);
          a = fmaf(xv.z, p[jj].z, a);
          a = fmaf(xv.w, p[jj].w, a);
          acc[t][jj] = a;
        }
      }
    }
    __syncthreads();
  }

  // ---- wave-reduce sumsq (tokens 2w, 2w+1) ----
#pragma unroll
  for (int d = 1; d < 64; d <<= 1) {
    ssq0 += __shfl_xor(ssq0, d, 64);
    ssq1 += __shfl_xor(ssq1, d, 64);
  }
  if (lane == 0) {
    lds_inv[2 * w]     = 1.0f / sqrtf(ssq0 * (1.0f / STREAM) + 1e-20f);
    lds_inv[2 * w + 1] = 1.0f / sqrtf(ssq1 * (1.0f / STREAM) + 1e-20f);
  }

  // ---- wave-reduce the 48 accumulators (butterfly; all lanes get totals) ----
#pragma unroll
  for (int d = 1; d < 64; d <<= 1) {
#pragma unroll
    for (int t = 0; t < T_PER_BLOCK; t++)
#pragma unroll
      for (int jj = 0; jj < 6; jj++)
        acc[t][jj] += __shfl_xor(acc[t][jj], d, 64);
  }
  __syncthreads();   // lds_inv visible to all waves

  // ---- write m: lane t*6+jj stores token tok0+t, column j=6w+jj ----
#pragma unroll
  for (int t = 0; t < T_PER_BLOCK; t++) {
    float inv = lds_inv[t];
#pragma unroll
    for (int jj = 0; jj < 6; jj++) {
      if (lane == t * 6 + jj) {
        int j = 6 * w + jj;
        m_buf[(tok0 + t) * NOUT + j] = acc[t][jj] * inv + bias[j];
      }
    }
  }
}

// ---------------------------------------------------------------------------
// Kernel C: heads + Sinkhorn. 16 lanes per token (one per 4x4 element).
//   row sums: shfl_xor 1,2 (c bits); col sums: shfl_xor 4,8 (r bits).
// ---------------------------------------------------------------------------
__global__ __launch_bounds__(256) void k_heads(
    const float* __restrict__ m_buf, const float* __restrict__ a_pre_p,
    const float* __restrict__ a_post_p, const float* __restrict__ a_res_p,
    float* __restrict__ out) {
  int gid = blockIdx.x * 256 + threadIdx.x;
  int tok = gid >> 4;
  int e   = gid & 15;          // r*4 + c

  float a_res = *a_res_p;
  float M = expf(a_res * m_buf[tok * NOUT + 2 * NEXP + e]);
#pragma unroll 1
  for (int it = 0; it < SK_ITERS; it++) {
    float rs = M + __shfl_xor(M, 1, 64);
    rs += __shfl_xor(rs, 2, 64);
    M = M / (rs + 1e-12f);
    float cs = M + __shfl_xor(M, 4, 64);
    cs += __shfl_xor(cs, 8, 64);
    M = M / (cs + 1e-12f);
  }
  out[2 * NTOK * NEXP + tok * 16 + e] = M;   // h_res at offset 131072

  if (e < NEXP) {
    float z = (*a_pre_p) * m_buf[tok * NOUT + e];
    out[tok * NEXP + e] = 1.0f / (1.0f + expf(-z));
  } else if (e < 2 * NEXP) {
    int j = e - NEXP;
    float z = (*a_post_p) * m_buf[tok * NOUT + NEXP + j];
    out[NTOK * NEXP + tok * NEXP + j] = 2.0f / (1.0f + expf(-z));
  }
}

// ---------------------------------------------------------------------------
extern "C" void kernel_launch(void* const* d_in, const int* in_sizes, int n_in,
                              void* d_out, int out_size, void* d_ws, size_t ws_size,
                              hipStream_t stream) {
  const float* x      = (const float*)d_in[0];
  const float* scale  = (const float*)d_in[1];
  const float* phi    = (const float*)d_in[2];
  const float* bias   = (const float*)d_in[3];
  const float* a_pre  = (const float*)d_in[4];
  const float* a_post = (const float*)d_in[5];
  const float* a_res  = (const float*)d_in[6];
  float* out = (float*)d_out;

  float* phiT  = (float*)d_ws;            // 24*4096 = 98304 floats
  float* m_buf = phiT + NOUT * STREAM;    // 16384*24 = 393216 floats

  k_transpose_scale<<<(NOUT * STREAM) / 256, 256, 0, stream>>>(phi, scale, phiT);
  k_matvec<<<NTOK / T_PER_BLOCK, 256, 0, stream>>>(x, phiT, bias, m_buf);
  k_heads<<<(NTOK * 16) / 256, 256, 0, stream>>>(m_buf, a_pre, a_post, a_res, out);
}